// Round 4
// baseline (229.029 us; speedup 1.0000x reference)
//
#include <hip/hip_runtime.h>
#include <stdint.h>

// Problem constants (fixed by setup_inputs): img (8,3,512,1024) f32, flo (8,2,512,1024) f32
constexpr int Nn = 8;
constexpr int Cc = 3;
constexpr int Hh = 512;
constexpr int Ww = 1024;
constexpr int HW = Hh * Ww;           // 524288
constexpr int NCHW = Nn * Cc * HW;    // 12582912

// Measured model (R0/R2/R3): LDS atomics serialize at ~3.3 cyc per LANE-op
// per CU (76M->352us, 94M->525us, 16.8M bumps->99.6us), all other pipes idle.
// This round: ONE ds_add_rtn_u32 per source PATCH (not per corner) -- the 4
// corners of a source share {i0,i1,i2,fx,fy}; the epilogue reconstructs the
// 4 weights exp(-((fx-a)^2+(fy-b)^2)), a,b in {0,1}. Bumps: 16.8M -> 4.6M.
constexpr int TH = 16;                // owned output tile height
constexpr int TW = 32;                // owned output tile width
constexpr int R  = 4;                 // tiled pass handles patches with floor-offset
                                      // in [-R, R-1] per axis (<=> flow in [-4,4));
                                      // everything else -> exact rescan fixup.
constexpr int RH = TH + 2 * R;        // 24 source-region height
constexpr int RW = TW + 2 * R;        // 40 source-region width
constexpr int NPIX = RH * RW;         // 960
constexpr int ITERS = (NPIX + 255) / 256;   // 4
constexpr int TILE_PIX = TH * TW;     // 512
constexpr int NP = (TH + 1) * (TW + 1);     // 561 anchor positions (ext. up/left)
constexpr int SLOTS = 5;              // patches/anchor ~ Poisson(1); P(K>5)=5.9e-4
                                      // -> ~2.7k overflow sources total (cheap path).

typedef float fvec4 __attribute__((ext_vector_type(4)));
typedef __attribute__((address_space(3))) float lds_f;

// Overflow path: 4 hardware LDS f32 atomic adds (planes TILE_PIX*4 = 2048 B apart).
__device__ __forceinline__ void ds_fadd4(lds_f* p, float a, float b, float c, float d) {
    asm volatile(
        "ds_add_f32 %0, %1\n\t"
        "ds_add_f32 %0, %2 offset:2048\n\t"
        "ds_add_f32 %0, %3 offset:4096\n\t"
        "ds_add_f32 %0, %4 offset:6144"
        :: "v"(p), "v"(a), "v"(b), "v"(c), "v"(d) : "memory");
}

// -------------------------------------------------------------------------
// splat_tiled: one block per 16x32 output tile. Register-staged halo loads.
// Per in-partition source: 1 atomic u32 bump on its ANCHOR (corner-11 target)
// + 5 plain LDS writes {i0,i1,i2,fx,fy}. Anchor domain is (TH+1)x(TW+1)
// (one extra row above / col left); boundary anchors are recorded by both
// adjacent blocks, but each block's epilogue applies only its OWN pixels ->
// every (source,target) pair applied exactly once. Epilogue: each pixel
// gathers its 4 neighboring anchor lists, reconstructing weights via __expf.
// LDS: cnt 2.2KB + slots 56.1KB + ovf 8KB = 66.5KB -> 2 blocks/CU.
// -------------------------------------------------------------------------
__global__ __launch_bounds__(256, 2) void splat_tiled(
        const float* __restrict__ img,
        const float* __restrict__ flo,
        float* __restrict__ out) {                // imgw at out, o at out+NCHW
    __shared__ unsigned int s_cnt[NP];            // 2244 B
    __shared__ float s_slot[SLOTS * NP * 5];      // 56100 B, entry (j,a) at (j*NP+a)*5
    __shared__ float s_ovf[4 * TILE_PIX];         // 8192 B
    const int tid = threadIdx.x;
    for (int i = tid; i < NP; i += 256) s_cnt[i] = 0u;
    {
        fvec4* a4 = (fvec4*)s_ovf;
        fvec4 z = {0.f, 0.f, 0.f, 0.f};
        a4[tid]       = z;
        a4[tid + 256] = z;
    }
    __syncthreads();

    const int tw0 = blockIdx.x * TW;
    const int th0 = blockIdx.y * TH;
    const int n   = blockIdx.z;
    const float* __restrict__ floy = flo + (size_t)(n * 2 + 0) * HW;  // indexes W axis
    const float* __restrict__ flox = flo + (size_t)(n * 2 + 1) * HW;  // indexes H axis
    const float* __restrict__ imgn = img + (size_t)n * Cc * HW;

    // ---- Phase A: issue ALL halo loads (clamped addresses; masking later) ----
    float sy[ITERS], sx[ITERS], u0[ITERS], u1[ITERS], u2[ITERS];
    #pragma unroll
    for (int it = 0; it < ITERS; ++it) {
        int i  = tid + 256 * it;
        int ic = i < NPIX ? i : NPIX - 1;
        int rh = ic / RW;
        int rw = ic - rh * RW;
        int h  = th0 - R + rh;
        int w  = tw0 - R + rw;
        int hc = h < 0 ? 0 : (h > Hh - 1 ? Hh - 1 : h);
        int wc = w < 0 ? 0 : (w > Ww - 1 ? Ww - 1 : w);
        int hwc = hc * Ww + wc;
        sy[it] = floy[hwc];
        sx[it] = flox[hwc];
        u0[it] = imgn[hwc];
        u1[it] = imgn[HW + hwc];
        u2[it] = imgn[2 * HW + hwc];
    }

    // ---- Phase B: anchor-slot scatter (no exp, no per-corner atomics) ----
    #pragma unroll
    for (int it = 0; it < ITERS; ++it) {
        int i  = tid + 256 * it;
        int rh = i / RW;
        int rw = i - rh * RW;
        int h  = th0 - R + rh;
        int w  = tw0 - R + rw;
        bool live = (i < NPIX) & (h >= 0) & (h < Hh) & (w >= 0) & (w < Ww);

        float y = sy[it], x = sx[it];
        float x1f = floorf(x), y1f = floorf(y);
        float fx = x - x1f, fy = y - y1f;
        int ox = (int)x1f, oy = (int)y1f;
        // Patch-level partition: corners have offsets {ox,ox+1}x{oy,oy+1};
        // tiled pass owns the patch iff ox,oy in [-R, R-1] (<=> flow in [-4,4)).
        bool patchok = (ox >= -R) & (ox <= R - 1) & (oy >= -R) & (oy <= R - 1);
        int ah = ox + rh - R;      // anchor local row in [-1, TH-1] if relevant
        int aw = oy + rw - R;      // anchor local col in [-1, TW-1]
        bool rec = live & patchok & (ah >= -1) & (ah <= TH - 1)
                                  & (aw >= -1) & (aw <= TW - 1);
        if (rec) {
            int aIdx = (ah + 1) * (TW + 1) + (aw + 1);
            unsigned int idx = atomicAdd(&s_cnt[aIdx], 1u);   // ds_add_rtn_u32
            if (idx < (unsigned)SLOTS) {
                float* e = &s_slot[((int)idx * NP + aIdx) * 5];
                e[0] = u0[it];
                e[1] = u1[it];
                e[2] = u2[it];
                e[3] = fx;
                e[4] = fy;
            } else {
                // rare overflow: apply in-tile corners with f32 LDS atomics
                float i0 = u0[it], i1 = u1[it], i2 = u2[it];
                #pragma unroll
                for (int a = 0; a < 2; ++a) {
                    #pragma unroll
                    for (int b = 0; b < 2; ++b) {
                        int t_h = ah + a, t_w = aw + b;
                        if ((unsigned)t_h < (unsigned)TH && (unsigned)t_w < (unsigned)TW) {
                            float dx = fx - (float)a, dy = fy - (float)b;
                            float wt = __expf(-(dx * dx + dy * dy));
                            ds_fadd4((lds_f*)s_ovf + (t_h * TW + t_w),
                                     i0 * wt, i1 * wt, i2 * wt, wt);
                        }
                    }
                }
            }
        }
    }
    __syncthreads();

    // ---- Epilogue: gather 4 anchor lists per pixel, coalesced stores ----
    float* __restrict__ imgw  = out;
    float* __restrict__ o_out = out + NCHW;
    const size_t nb = (size_t)n * Cc * HW;
    #pragma unroll
    for (int itr = 0; itr < 2; ++itr) {           // 512 pixels / 256 threads
        int pix = tid + 256 * itr;
        int lh = pix >> 5, lw = pix & 31;         // TW = 32
        float s0 = s_ovf[pix];
        float s1 = s_ovf[TILE_PIX + pix];
        float s2 = s_ovf[2 * TILE_PIX + pix];
        float s3 = s_ovf[3 * TILE_PIX + pix];
        #pragma unroll
        for (int a = 0; a < 2; ++a) {
            #pragma unroll
            for (int b = 0; b < 2; ++b) {
                // contribution from anchor (lh-a, lw-b): corner (a,b) -> this pixel
                int aIdx = (lh - a + 1) * (TW + 1) + (lw - b + 1);
                unsigned int k = s_cnt[aIdx];
                if (k > (unsigned)SLOTS) k = SLOTS;
                #pragma unroll
                for (int j = 0; j < SLOTS; ++j) {
                    if ((unsigned)j < k) {
                        const float* e = &s_slot[(j * NP + aIdx) * 5];
                        float e0 = e[0], e1 = e[1], e2 = e[2];
                        float dx = e[3] - (float)a, dy = e[4] - (float)b;
                        float wt = __expf(-(dx * dx + dy * dy));
                        s0 += e0 * wt;
                        s1 += e1 * wt;
                        s2 += e2 * wt;
                        s3 += wt;
                    }
                }
            }
        }
        size_t hw = (size_t)(th0 + lh) * Ww + (tw0 + lw);
        __builtin_nontemporal_store(s0, imgw + nb + hw);
        __builtin_nontemporal_store(s1, imgw + nb + HW + hw);
        __builtin_nontemporal_store(s2, imgw + nb + 2 * HW + hw);
        __builtin_nontemporal_store(s3, o_out + nb + hw);
        __builtin_nontemporal_store(s3, o_out + nb + HW + hw);
        __builtin_nontemporal_store(s3, o_out + nb + 2 * HW + hw);
    }
}

// -------------------------------------------------------------------------
// rescan_all: exact fixup for patches the tiled pass skipped (flow outside
// [-4,4) on some axis; ~530 px expected for N(0,1)). One fvec4-group per
// thread, 4096 blocks -- a 33.5 MB scan with wave-level early exit. Runs
// AFTER splat_tiled (its atomics must not race the tiles' plain stores).
// -------------------------------------------------------------------------
__global__ __launch_bounds__(256) void rescan_all(
        const float* __restrict__ img,
        const float* __restrict__ flo,
        float* __restrict__ out) {
    float* imgw  = out;
    float* o_out = out + NCHW;
    unsigned int j = blockIdx.x * blockDim.x + threadIdx.x;
    if (j >= (unsigned)(Nn * HW / 4)) return;
    int n   = j / (HW / 4);
    int q   = j - n * (HW / 4);
    int hw0 = q * 4;
    const fvec4 y4 = *(const fvec4*)&flo[(size_t)(n * 2 + 0) * HW + hw0];
    const fvec4 x4 = *(const fvec4*)&flo[(size_t)(n * 2 + 1) * HW + hw0];
    #pragma unroll
    for (int k = 0; k < 4; ++k) {
        float x = x4[k], y = y4[k];
        // skip iff the tiled pass owned the whole patch: flow in [-4,4) both axes
        if (x >= -(float)R && x < (float)R && y >= -(float)R && y < (float)R) continue;
        int hw = hw0 + k;
        int h = hw >> 10;            // Ww = 1024
        int w = hw & (Ww - 1);
        float x1f = floorf(x), y1f = floorf(y);
        float fx = x - x1f, fy = y - y1f;
        int bx = (int)x1f, by = (int)y1f;
        float i0 = img[(size_t)(n * Cc + 0) * HW + hw];
        float i1 = img[(size_t)(n * Cc + 1) * HW + hw];
        float i2 = img[(size_t)(n * Cc + 2) * HW + hw];
        const size_t nb = (size_t)n * Cc * HW;
        #pragma unroll
        for (int a = 0; a < 2; ++a) {
            #pragma unroll
            for (int b = 0; b < 2; ++b) {
                int ix = h + bx + a;
                int iy = w + by + b;
                if (ix < 0 || ix >= Hh || iy < 0 || iy >= Ww) continue;
                float dx = fx - (float)a, dy = fy - (float)b;
                float wt = __expf(-(dx * dx + dy * dy));
                int t = ix * Ww + iy;
                atomicAdd(&imgw[nb + t], i0 * wt);
                atomicAdd(&imgw[nb + HW + t], i1 * wt);
                atomicAdd(&imgw[nb + 2 * HW + t], i2 * wt);
                atomicAdd(&o_out[nb + t], wt);
                atomicAdd(&o_out[nb + HW + t], wt);
                atomicAdd(&o_out[nb + 2 * HW + t], wt);
            }
        }
    }
}

extern "C" void kernel_launch(void* const* d_in, const int* in_sizes, int n_in,
                              void* d_out, int out_size, void* d_ws, size_t ws_size,
                              hipStream_t stream) {
    const float* img = (const float*)d_in[0];
    const float* flo = (const float*)d_in[1];
    float* out = (float*)d_out;
    (void)d_ws; (void)ws_size;

    dim3 block(256);
    dim3 grid(Ww / TW, Hh / TH, Nn);   // 32 x 32 x 8 = 8192 blocks
    splat_tiled<<<grid, block, 0, stream>>>(img, flo, out);
    rescan_all<<<(Nn * HW / 4 + 255) / 256, 256, 0, stream>>>(img, flo, out);
}

// Round 5
// 208.972 us; speedup vs baseline: 1.0960x; 1.0960x over previous
//
#include <hip/hip_runtime.h>
#include <stdint.h>

// Problem constants (fixed by setup_inputs): img (8,3,512,1024) f32, flo (8,2,512,1024) f32
constexpr int Nn = 8;
constexpr int Cc = 3;
constexpr int Hh = 512;
constexpr int Ww = 1024;
constexpr int HW = Hh * Ww;           // 524288
constexpr int NCHW = Nn * Cc * HW;    // 12582912

// Measured model (R0/R2/R3/R4): LDS *atomics* serialize at ~3.3 cyc/lane-op
// per CU; plain ds ops are ~30x cheaper. R4 showed the epilogue's empty-slot
// reads + 2-block occupancy matter as much as the allocator. This round:
//  - slot 0 allocated by CLAIM/READBACK (plain b32 write, barrier, read) --
//    key (anchor,ox,oy) is unique per source, so the surviving tag identifies
//    exactly one winner; no atomic for ~74% of sources.
//  - losers (mean 0.26/anchor) bump a packed u8 counter into 3 compact
//    overflow slots; >=4th contender (~2/block) -> ds_add_f32 planes.
//  - 16B payload {i0,i1,i2,pack16(fx,fy)} = ONE ds_write_b128/read_b128.
//  - LDS 46.9KB -> 3 blocks/CU (12 waves).
constexpr int TH = 16;                // owned output tile height
constexpr int TW = 32;                // owned output tile width
constexpr int R  = 4;                 // tiled pass owns patches with floor(flow) in
                                      // [-R,R-1] per axis (<=> flow in [-4,4));
                                      // rest -> exact rescan fixup (~530 px).
constexpr int RH = TH + 2 * R;        // 24 source-region height
constexpr int RW = TW + 2 * R;        // 40 source-region width
constexpr int NPIX = RH * RW;         // 960
constexpr int ITERS = (NPIX + 255) / 256;   // 4
constexpr int TILE_PIX = TH * TW;     // 512
constexpr int AWP = TW + 1;           // 33 anchor cols (ext. one col left)
constexpr int NP  = (TH + 1) * AWP;   // 561 anchor positions (ext. up/left)
constexpr int OVF_SLOTS = 3;          // compact loser slots per anchor

typedef float fvec4 __attribute__((ext_vector_type(4)));
typedef __attribute__((address_space(3))) float lds_f;

// Rare fallback: 4 hardware LDS f32 atomic adds (planes TILE_PIX*4 = 2048 B apart).
__device__ __forceinline__ void ds_fadd4(lds_f* p, float a, float b, float c, float d) {
    asm volatile(
        "ds_add_f32 %0, %1\n\t"
        "ds_add_f32 %0, %2 offset:2048\n\t"
        "ds_add_f32 %0, %3 offset:4096\n\t"
        "ds_add_f32 %0, %4 offset:6144"
        :: "v"(p), "v"(a), "v"(b), "v"(c), "v"(d) : "memory");
}

// -------------------------------------------------------------------------
// splat_tiled: one block per 16x32 output tile (XCD-remapped: batch n =
// linear_block_id % 8 so each XCD's private L2 sees one image only).
// Phase A: register-stage all halo loads. B1: claim tags. B2: winners write
// payload b128; losers bump into overflow; deep overflow -> atomic planes.
// Epilogue: per pixel gather 4 anchors {tag, payload, ovf[k]}, reconstruct
// Gaussian weights, coalesced nontemporal stores.
// -------------------------------------------------------------------------
__global__ __launch_bounds__(256, 3) void splat_tiled(
        const float* __restrict__ img,
        const float* __restrict__ flo,
        float* __restrict__ out) {                // imgw at out, o at out+NCHW
    __shared__ unsigned int s_tag[NP];                 // 2244 B  claim tags
    __shared__ unsigned int s_ocnt[(NP + 3) / 4];      //  564 B  packed u8 loser counts
    __shared__ alignas(16) float s_pay[NP * 4];        // 8976 B  slot-0 payloads
    __shared__ alignas(16) float s_ovf[OVF_SLOTS * NP * 4];  // 26928 B loser payloads
    __shared__ float s_pl[4 * TILE_PIX];               // 8192 B  atomic fallback planes
    const int tid = threadIdx.x;
    for (int i = tid; i < NP; i += 256) s_tag[i] = 0u;
    for (int i = tid; i < (NP + 3) / 4; i += 256) s_ocnt[i] = 0u;
    {
        fvec4* a4 = (fvec4*)s_pl;
        fvec4 z = {0.f, 0.f, 0.f, 0.f};
        a4[tid] = z;
        a4[tid + 256] = z;
    }
    __syncthreads();

    // XCD-aware remap: hardware dispatch round-robins linear block id over
    // XCDs; linear%8 -> batch image puts each image's tiles on one XCD.
    const int lin = blockIdx.x + 32 * blockIdx.y + 1024 * blockIdx.z;
    const int n   = lin & 7;
    const int t   = lin >> 3;                     // 0..1023
    const int tw0 = (t & 31) * TW;
    const int th0 = (t >> 5) * TH;
    const float* __restrict__ floy = flo + (size_t)(n * 2 + 0) * HW;  // indexes W axis
    const float* __restrict__ flox = flo + (size_t)(n * 2 + 1) * HW;  // indexes H axis
    const float* __restrict__ imgn = img + (size_t)n * Cc * HW;

    // ---- Phase A: issue ALL halo loads (clamped addresses; masking later) ----
    float sy[ITERS], sx[ITERS], u0[ITERS], u1[ITERS], u2[ITERS];
    #pragma unroll
    for (int it = 0; it < ITERS; ++it) {
        int i  = tid + 256 * it;
        int ic = i < NPIX ? i : NPIX - 1;
        int rh = ic / RW;
        int rw = ic - rh * RW;
        int h  = th0 - R + rh;
        int w  = tw0 - R + rw;
        int hc = h < 0 ? 0 : (h > Hh - 1 ? Hh - 1 : h);
        int wc = w < 0 ? 0 : (w > Ww - 1 ? Ww - 1 : w);
        int hwc = hc * Ww + wc;
        sy[it] = floy[hwc];
        sx[it] = flox[hwc];
        u0[it] = imgn[hwc];
        u1[it] = imgn[HW + hwc];
        u2[it] = imgn[2 * HW + hwc];
    }

    // ---- Phase B1: compute anchors + plain-write claim tags ----
    int aA[ITERS];
    unsigned int tg[ITERS], fxy[ITERS];
    #pragma unroll
    for (int it = 0; it < ITERS; ++it) {
        int i  = tid + 256 * it;
        int rh = i / RW;
        int rw = i - rh * RW;
        int h  = th0 - R + rh;
        int w  = tw0 - R + rw;
        bool live = (i < NPIX) & (h >= 0) & (h < Hh) & (w >= 0) & (w < Ww);

        float y = sy[it], x = sx[it];
        float x1f = floorf(x), y1f = floorf(y);
        float fx = x - x1f, fy = y - y1f;
        int ox = (int)x1f, oy = (int)y1f;
        bool patchok = (ox >= -R) & (ox <= R - 1) & (oy >= -R) & (oy <= R - 1);
        int ah = ox + rh - R;      // anchor local row in [-1, TH-1] if relevant
        int aw = oy + rw - R;      // anchor local col in [-1, TW-1]
        bool rec = live & patchok & (ah >= -1) & (ah <= TH - 1)
                                  & (aw >= -1) & (aw <= TW - 1);
        int aIdx = (ah + 1) * AWP + (aw + 1);
        // tag: valid bit | (ox+4)<<24 | (oy+4)<<16 -- unique among an anchor's
        // contenders (same anchor + same (ox,oy) => same source).
        tg[it]  = 0x80000000u | ((unsigned)(ox + 4) << 24) | ((unsigned)(oy + 4) << 16);
        fxy[it] = (unsigned)(fx * 65535.0f + 0.5f)
                | ((unsigned)(fy * 65535.0f + 0.5f) << 16);
        aA[it]  = rec ? aIdx : -1;
        if (rec) s_tag[aIdx] = tg[it];            // plain b32; HW picks one winner
    }
    __syncthreads();

    // ---- Phase B2: readback; winner -> payload b128; loser -> overflow ----
    #pragma unroll
    for (int it = 0; it < ITERS; ++it) {
        int a = aA[it];
        if (a >= 0) {
            if (s_tag[a] == tg[it]) {             // survived: own slot 0
                fvec4 e = {u0[it], u1[it], u2[it], __uint_as_float(fxy[it])};
                *(fvec4*)&s_pay[a * 4] = e;       // contention-free ds_write_b128
            } else {                              // loser: compact overflow
                unsigned sh  = 8u * (unsigned)(a & 3);
                unsigned old = atomicAdd(&s_ocnt[a >> 2], 1u << sh); // ds_add_rtn_u32
                unsigned idx = (old >> sh) & 0xFFu;
                if (idx < (unsigned)OVF_SLOTS) {
                    fvec4 e = {u0[it], u1[it], u2[it], __uint_as_float(fxy[it])};
                    *(fvec4*)&s_ovf[((int)idx * NP + a) * 4] = e;
                } else {                          // ~2 sources/block: atomic planes
                    int ah = a / AWP - 1;
                    int aw = a - (ah + 1) * AWP - 1;
                    float fx = (float)(fxy[it] & 0xFFFFu) * (1.0f / 65535.0f);
                    float fy = (float)(fxy[it] >> 16) * (1.0f / 65535.0f);
                    #pragma unroll
                    for (int ca = 0; ca < 2; ++ca) {
                        #pragma unroll
                        for (int cb = 0; cb < 2; ++cb) {
                            int t_h = ah + ca, t_w = aw + cb;
                            if ((unsigned)t_h < (unsigned)TH && (unsigned)t_w < (unsigned)TW) {
                                float dx = fx - (float)ca, dy = fy - (float)cb;
                                float wt = __expf(-(dx * dx + dy * dy));
                                ds_fadd4((lds_f*)s_pl + (t_h * TW + t_w),
                                         u0[it] * wt, u1[it] * wt, u2[it] * wt, wt);
                            }
                        }
                    }
                }
            }
        }
    }
    __syncthreads();

    // ---- Epilogue: gather 4 anchors per pixel, coalesced stores ----
    float* __restrict__ imgw  = out;
    float* __restrict__ o_out = out + NCHW;
    const size_t nb = (size_t)n * Cc * HW;
    const fvec4* pay4 = (const fvec4*)s_pay;
    const fvec4* ovf4 = (const fvec4*)s_ovf;
    #pragma unroll
    for (int itr = 0; itr < 2; ++itr) {           // 512 pixels / 256 threads
        int pix = tid + 256 * itr;
        int lh = pix >> 5, lw = pix & 31;         // TW = 32
        float s0 = s_pl[pix];
        float s1 = s_pl[TILE_PIX + pix];
        float s2 = s_pl[2 * TILE_PIX + pix];
        float s3 = s_pl[3 * TILE_PIX + pix];
        #pragma unroll
        for (int a = 0; a < 2; ++a) {
            #pragma unroll
            for (int b = 0; b < 2; ++b) {
                // anchor (lh-a, lw-b): its corner (a,b) lands on this pixel
                int ai = (lh - a + 1) * AWP + (lw - b + 1);
                unsigned tgv = s_tag[ai];
                if (tgv & 0x80000000u) {
                    fvec4 e = pay4[ai];
                    unsigned p = __float_as_uint(e[3]);
                    float fx = (float)(p & 0xFFFFu) * (1.0f / 65535.0f);
                    float fy = (float)(p >> 16) * (1.0f / 65535.0f);
                    float dx = fx - (float)a, dy = fy - (float)b;
                    float wt = __expf(-(dx * dx + dy * dy));
                    s0 += e[0] * wt; s1 += e[1] * wt; s2 += e[2] * wt; s3 += wt;
                }
                unsigned k = (s_ocnt[ai >> 2] >> (8u * (unsigned)(ai & 3))) & 0xFFu;
                #pragma unroll
                for (int j = 0; j < OVF_SLOTS; ++j) {
                    if (j < (int)k) {
                        fvec4 e = ovf4[j * NP + ai];
                        unsigned p = __float_as_uint(e[3]);
                        float fx = (float)(p & 0xFFFFu) * (1.0f / 65535.0f);
                        float fy = (float)(p >> 16) * (1.0f / 65535.0f);
                        float dx = fx - (float)a, dy = fy - (float)b;
                        float wt = __expf(-(dx * dx + dy * dy));
                        s0 += e[0] * wt; s1 += e[1] * wt; s2 += e[2] * wt; s3 += wt;
                    }
                }
            }
        }
        size_t hw = (size_t)(th0 + lh) * Ww + (tw0 + lw);
        __builtin_nontemporal_store(s0, imgw + nb + hw);
        __builtin_nontemporal_store(s1, imgw + nb + HW + hw);
        __builtin_nontemporal_store(s2, imgw + nb + 2 * HW + hw);
        __builtin_nontemporal_store(s3, o_out + nb + hw);
        __builtin_nontemporal_store(s3, o_out + nb + HW + hw);
        __builtin_nontemporal_store(s3, o_out + nb + 2 * HW + hw);
    }
}

// -------------------------------------------------------------------------
// rescan_all: exact fixup for patches the tiled pass skipped (flow outside
// [-4,4) on some axis; ~530 px expected for N(0,1)). 33.5 MB coalesced scan
// with early exit. Must run AFTER splat_tiled (atomics vs plain stores).
// -------------------------------------------------------------------------
__global__ __launch_bounds__(256) void rescan_all(
        const float* __restrict__ img,
        const float* __restrict__ flo,
        float* __restrict__ out) {
    float* imgw  = out;
    float* o_out = out + NCHW;
    unsigned int j = blockIdx.x * blockDim.x + threadIdx.x;
    if (j >= (unsigned)(Nn * HW / 4)) return;
    int n   = j / (HW / 4);
    int q   = j - n * (HW / 4);
    int hw0 = q * 4;
    const fvec4 y4 = *(const fvec4*)&flo[(size_t)(n * 2 + 0) * HW + hw0];
    const fvec4 x4 = *(const fvec4*)&flo[(size_t)(n * 2 + 1) * HW + hw0];
    #pragma unroll
    for (int k = 0; k < 4; ++k) {
        float x = x4[k], y = y4[k];
        // skip iff the tiled pass owned the whole patch: flow in [-4,4) both axes
        if (x >= -(float)R && x < (float)R && y >= -(float)R && y < (float)R) continue;
        int hw = hw0 + k;
        int h = hw >> 10;            // Ww = 1024
        int w = hw & (Ww - 1);
        float x1f = floorf(x), y1f = floorf(y);
        float fx = x - x1f, fy = y - y1f;
        int bx = (int)x1f, by = (int)y1f;
        float i0 = img[(size_t)(n * Cc + 0) * HW + hw];
        float i1 = img[(size_t)(n * Cc + 1) * HW + hw];
        float i2 = img[(size_t)(n * Cc + 2) * HW + hw];
        const size_t nb = (size_t)n * Cc * HW;
        #pragma unroll
        for (int a = 0; a < 2; ++a) {
            #pragma unroll
            for (int b = 0; b < 2; ++b) {
                int ix = h + bx + a;
                int iy = w + by + b;
                if (ix < 0 || ix >= Hh || iy < 0 || iy >= Ww) continue;
                float dx = fx - (float)a, dy = fy - (float)b;
                float wt = __expf(-(dx * dx + dy * dy));
                int t = ix * Ww + iy;
                atomicAdd(&imgw[nb + t], i0 * wt);
                atomicAdd(&imgw[nb + HW + t], i1 * wt);
                atomicAdd(&imgw[nb + 2 * HW + t], i2 * wt);
                atomicAdd(&o_out[nb + t], wt);
                atomicAdd(&o_out[nb + HW + t], wt);
                atomicAdd(&o_out[nb + 2 * HW + t], wt);
            }
        }
    }
}

extern "C" void kernel_launch(void* const* d_in, const int* in_sizes, int n_in,
                              void* d_out, int out_size, void* d_ws, size_t ws_size,
                              hipStream_t stream) {
    const float* img = (const float*)d_in[0];
    const float* flo = (const float*)d_in[1];
    float* out = (float*)d_out;
    (void)d_ws; (void)ws_size;

    dim3 block(256);
    dim3 grid(32, 32, 8);   // remapped internally: n = linear%8 (XCD-local images)
    splat_tiled<<<grid, block, 0, stream>>>(img, flo, out);
    rescan_all<<<(Nn * HW / 4 + 255) / 256, 256, 0, stream>>>(img, flo, out);
}

// Round 6
// 191.065 us; speedup vs baseline: 1.1987x; 1.0937x over previous
//
#include <hip/hip_runtime.h>
#include <hip/hip_fp16.h>
#include <stdint.h>

// Problem constants (fixed by setup_inputs): img (8,3,512,1024) f32, flo (8,2,512,1024) f32
constexpr int Nn = 8;
constexpr int Cc = 3;
constexpr int Hh = 512;
constexpr int Ww = 1024;
constexpr int HW = Hh * Ww;           // 524288
constexpr int NCHW = Nn * Cc * HW;    // 12582912

// Measured model (R0-R5): LDS atomics serialize ~3.3 cyc/lane-op per CU;
// claims (plain write | barrier | readback) allocate slots with ZERO atomics
// and cost the same LDS as bump-allocated slots. This round: 3 claim rounds
// reusing ONE tag array; winners plain-write payload + a byte count (rounds
// are barrier-ordered, so last writer = deepest round). Only >=4th contender
// per anchor (~3.5 sources/block) falls to ds_add_f32 planes. Payload packed
// to 12 B (f16-rn imgs + 16-bit fixed fx,fy) -> 30.5 KB LDS -> 5 blocks/CU.
constexpr int TH = 16;                // owned output tile height
constexpr int TW = 32;                // owned output tile width
constexpr int R  = 4;                 // tiled pass owns patches with floor(flow) in
                                      // [-R,R-1] per axis (<=> flow in [-4,4));
                                      // rest -> exact rescan fixup (~530 px).
constexpr int RH = TH + 2 * R;        // 24 source-region height
constexpr int RW = TW + 2 * R;        // 40 source-region width
constexpr int NPIX = RH * RW;         // 960
constexpr int ITERS = (NPIX + 255) / 256;   // 4
constexpr int TILE_PIX = TH * TW;     // 512
constexpr int AWP = TW + 1;           // 33 anchor cols (ext. one col left)
constexpr int NP  = (TH + 1) * AWP;   // 561 anchor positions (ext. up/left)
constexpr int NSLOT = 3;              // claim-allocated entry slots per anchor

typedef float fvec4 __attribute__((ext_vector_type(4)));
typedef float fvec2 __attribute__((ext_vector_type(2)));
typedef __attribute__((address_space(3))) float lds_f;

// Final-guard path: 4 hardware LDS f32 atomic adds (planes 2048 B apart).
__device__ __forceinline__ void ds_fadd4(lds_f* p, float a, float b, float c, float d) {
    asm volatile(
        "ds_add_f32 %0, %1\n\t"
        "ds_add_f32 %0, %2 offset:2048\n\t"
        "ds_add_f32 %0, %3 offset:4096\n\t"
        "ds_add_f32 %0, %4 offset:6144"
        :: "v"(p), "v"(a), "v"(b), "v"(c), "v"(d) : "memory");
}

// -------------------------------------------------------------------------
// splat_tiled: one block per 16x32 output tile (XCD-remapped: n = linear%8).
// A: register-stage all halo loads. B0: compute+pack, write claim tags.
// Rounds 0..2: {readback -> winner writes 12B payload + kcnt byte} | barrier
// | {losers rewrite tags} | barrier. Deep losers (X>=4) -> f32 atomic planes.
// Epilogue: one 1x2 pixel pair per thread gathers 6 anchors (8 visits),
// reconstructs Gaussian weights, float2 nontemporal stores.
// LDS: tag 2244 + pay 20196 + kcnt 568 + planes 8192 = 31200 B -> 5 blocks/CU.
// -------------------------------------------------------------------------
__global__ __launch_bounds__(256, 5) void splat_tiled(
        const float* __restrict__ img,
        const float* __restrict__ flo,
        float* __restrict__ out) {                // imgw at out, o at out+NCHW
    __shared__ unsigned int s_tag[NP];            // claim tags
    __shared__ unsigned int s_pay[NSLOT * NP * 3];// 12B entries, anchor-major:
                                                  //   base = ai*9 + slot*3 (stride 9
                                                  //   words: gcd(9,32)=1, conflict-free)
    __shared__ unsigned int s_kcnt[(NP + 3) / 4 + 1];  // u8 counts, word-backed
    __shared__ float s_pl[4 * TILE_PIX];          // deep-overflow atomic planes
    const int tid = threadIdx.x;
    for (int i = tid; i < NP; i += 256) s_tag[i] = 0u;
    for (int i = tid; i < (NP + 3) / 4 + 1; i += 256) s_kcnt[i] = 0u;
    {
        fvec4* a4 = (fvec4*)s_pl;
        fvec4 z = {0.f, 0.f, 0.f, 0.f};
        a4[tid] = z;
        a4[tid + 256] = z;
    }
    __syncthreads();

    // XCD-aware remap: linear%8 -> batch image (each XCD's L2 sees one image).
    const int lin = blockIdx.x + 32 * blockIdx.y + 1024 * blockIdx.z;
    const int n   = lin & 7;
    const int t   = lin >> 3;                     // 0..1023
    const int tw0 = (t & 31) * TW;
    const int th0 = (t >> 5) * TH;
    const float* __restrict__ floy = flo + (size_t)(n * 2 + 0) * HW;  // indexes W axis
    const float* __restrict__ flox = flo + (size_t)(n * 2 + 1) * HW;  // indexes H axis
    const float* __restrict__ imgn = img + (size_t)n * Cc * HW;

    // ---- Phase A: issue ALL halo loads (clamped addresses; masking later) ----
    float sy[ITERS], sx[ITERS], u0[ITERS], u1[ITERS], u2[ITERS];
    #pragma unroll
    for (int it = 0; it < ITERS; ++it) {
        int i  = tid + 256 * it;
        int ic = i < NPIX ? i : NPIX - 1;
        int rh = ic / RW;
        int rw = ic - rh * RW;
        int h  = th0 - R + rh;
        int w  = tw0 - R + rw;
        int hc = h < 0 ? 0 : (h > Hh - 1 ? Hh - 1 : h);
        int wc = w < 0 ? 0 : (w > Ww - 1 ? Ww - 1 : w);
        int hwc = hc * Ww + wc;
        sy[it] = floy[hwc];
        sx[it] = flox[hwc];
        u0[it] = imgn[hwc];
        u1[it] = imgn[HW + hwc];
        u2[it] = imgn[2 * HW + hwc];
    }

    // ---- Phase B0: compute, pack 12B payload, write round-0 claim tags ----
    int aA[ITERS];
    unsigned int tg[ITERS], q0[ITERS], q1[ITERS], q2[ITERS];
    bool pend[ITERS];
    #pragma unroll
    for (int it = 0; it < ITERS; ++it) {
        int i  = tid + 256 * it;
        int rh = i / RW;
        int rw = i - rh * RW;
        int h  = th0 - R + rh;
        int w  = tw0 - R + rw;
        bool live = (i < NPIX) & (h >= 0) & (h < Hh) & (w >= 0) & (w < Ww);

        float y = sy[it], x = sx[it];
        float x1f = floorf(x), y1f = floorf(y);
        float fx = x - x1f, fy = y - y1f;
        int ox = (int)x1f, oy = (int)y1f;
        bool patchok = (ox >= -R) & (ox <= R - 1) & (oy >= -R) & (oy <= R - 1);
        int ah = ox + rh - R;      // anchor local row in [-1, TH-1] if relevant
        int aw = oy + rw - R;      // anchor local col in [-1, TW-1]
        bool rec = live & patchok & (ah >= -1) & (ah <= TH - 1)
                                  & (aw >= -1) & (aw <= TW - 1);
        int aIdx = (ah + 1) * AWP + (aw + 1);
        // tag: bit31 | (ox+4)<<3 | (oy+4) -- unique per anchor's contenders.
        tg[it] = 0x80000000u | ((unsigned)(ox + R) << 3) | (unsigned)(oy + R);
        unsigned h0 = __half_as_ushort(__float2half_rn(u0[it]));
        unsigned h1 = __half_as_ushort(__float2half_rn(u1[it]));
        unsigned h2 = __half_as_ushort(__float2half_rn(u2[it]));
        unsigned fxq = (unsigned)(fx * 65535.0f + 0.5f);
        unsigned fyq = (unsigned)(fy * 65535.0f + 0.5f);
        q0[it] = h0 | (h1 << 16);
        q1[it] = h2 | (fxq << 16);
        q2[it] = fyq;
        aA[it]  = aIdx;
        pend[it] = rec;
        if (rec) s_tag[aIdx] = tg[it];            // plain b32; stable at readback
    }
    __syncthreads();

    // ---- Claim rounds 0..2 (atomic-free slot allocation) ----
    #pragma unroll
    for (int r = 0; r < NSLOT; ++r) {
        #pragma unroll
        for (int it = 0; it < ITERS; ++it) {      // readback + winner writes
            if (pend[it] && s_tag[aA[it]] == tg[it]) {
                int base = aA[it] * 9 + r * 3;
                s_pay[base]     = q0[it];
                s_pay[base + 1] = q1[it];
                s_pay[base + 2] = q2[it];
                ((unsigned char*)s_kcnt)[aA[it]] = (unsigned char)(r + 1);
                pend[it] = false;
            } else if (r == NSLOT - 1 && pend[it]) {
                // deep loser (>=4th contender, ~3.5/block): f32 atomic planes
                int a = aA[it];
                int arow = a / AWP;
                int ah = arow - 1;
                int aw = a - arow * AWP - 1;
                float fx = (float)(q1[it] >> 16) * (1.0f / 65535.0f);
                float fy = (float)(q2[it] & 0xFFFFu) * (1.0f / 65535.0f);
                float i0 = __half2float(__ushort_as_half((unsigned short)(q0[it] & 0xFFFFu)));
                float i1 = __half2float(__ushort_as_half((unsigned short)(q0[it] >> 16)));
                float i2 = __half2float(__ushort_as_half((unsigned short)(q1[it] & 0xFFFFu)));
                #pragma unroll
                for (int ca = 0; ca < 2; ++ca) {
                    #pragma unroll
                    for (int cb = 0; cb < 2; ++cb) {
                        int t_h = ah + ca, t_w = aw + cb;
                        if ((unsigned)t_h < (unsigned)TH && (unsigned)t_w < (unsigned)TW) {
                            float dx = fx - (float)ca, dy = fy - (float)cb;
                            float wt = __expf(-(dx * dx + dy * dy));
                            ds_fadd4((lds_f*)s_pl + (t_h * TW + t_w),
                                     i0 * wt, i1 * wt, i2 * wt, wt);
                        }
                    }
                }
            }
        }
        __syncthreads();                          // readbacks done, tags stable
        if (r < NSLOT - 1) {
            #pragma unroll
            for (int it = 0; it < ITERS; ++it)    // losers re-claim for round r+1
                if (pend[it]) s_tag[aA[it]] = tg[it];
            __syncthreads();                      // claims stable before readback
        }
    }

    // ---- Epilogue: 1x2 pixel pair per thread, 6 anchors serve 8 visits ----
    float* __restrict__ imgw  = out;
    float* __restrict__ o_out = out + NCHW;
    const size_t nb = (size_t)n * Cc * HW;
    {
        int pix = 2 * tid;                        // lw even
        int lh = pix >> 5, lw = pix & 31;         // TW = 32
        fvec2 p0 = *(const fvec2*)&s_pl[pix];
        fvec2 p1 = *(const fvec2*)&s_pl[512 + pix];
        fvec2 p2 = *(const fvec2*)&s_pl[1024 + pix];
        fvec2 p3 = *(const fvec2*)&s_pl[1536 + pix];
        float s0a = p0[0], s0b = p0[1];
        float s1a = p1[0], s1b = p1[1];
        float s2a = p2[0], s2b = p2[1];
        float s3a = p3[0], s3b = p3[1];
        #pragma unroll
        for (int a = 0; a < 2; ++a) {             // anchor rows lh-1, lh (stored +1-a)
            int arow = (lh - a + 1) * AWP + lw;
            #pragma unroll
            for (int c = 0; c < 3; ++c) {         // stored anchor cols lw+c
                int ai = arow + c;
                int k = ((const unsigned char*)s_kcnt)[ai];
                #pragma unroll
                for (int j = 0; j < NSLOT; ++j) {
                    if (j < k) {
                        int base = ai * 9 + j * 3;
                        unsigned w0 = s_pay[base];
                        unsigned w1 = s_pay[base + 1];
                        unsigned w2 = s_pay[base + 2];
                        float h0 = __half2float(__ushort_as_half((unsigned short)(w0 & 0xFFFFu)));
                        float h1 = __half2float(__ushort_as_half((unsigned short)(w0 >> 16)));
                        float h2 = __half2float(__ushort_as_half((unsigned short)(w1 & 0xFFFFu)));
                        float fx = (float)(w1 >> 16) * (1.0f / 65535.0f);
                        float fy = (float)(w2 & 0xFFFFu) * (1.0f / 65535.0f);
                        float dx  = fx - (float)a;
                        float dxx = dx * dx;
                        if (c < 2) {              // -> px0 with b = 1-c
                            float dy = fy - (float)(1 - c);
                            float wt = __expf(-(dxx + dy * dy));
                            s0a += h0 * wt; s1a += h1 * wt; s2a += h2 * wt; s3a += wt;
                        }
                        if (c >= 1) {             // -> px1 with b = 2-c
                            float dy = fy - (float)(2 - c);
                            float wt = __expf(-(dxx + dy * dy));
                            s0b += h0 * wt; s1b += h1 * wt; s2b += h2 * wt; s3b += wt;
                        }
                    }
                }
            }
        }
        size_t hw = (size_t)(th0 + lh) * Ww + (tw0 + lw);   // 8B aligned (lw even)
        fvec2 v;
        v[0] = s0a; v[1] = s0b;
        __builtin_nontemporal_store(v, (fvec2*)(imgw + nb + hw));
        v[0] = s1a; v[1] = s1b;
        __builtin_nontemporal_store(v, (fvec2*)(imgw + nb + HW + hw));
        v[0] = s2a; v[1] = s2b;
        __builtin_nontemporal_store(v, (fvec2*)(imgw + nb + 2 * HW + hw));
        v[0] = s3a; v[1] = s3b;
        __builtin_nontemporal_store(v, (fvec2*)(o_out + nb + hw));
        __builtin_nontemporal_store(v, (fvec2*)(o_out + nb + HW + hw));
        __builtin_nontemporal_store(v, (fvec2*)(o_out + nb + 2 * HW + hw));
    }
}

// -------------------------------------------------------------------------
// rescan_all: exact fixup for patches the tiled pass skipped (flow outside
// [-4,4) on some axis; ~530 px expected for N(0,1)). 33.5 MB coalesced scan
// with early exit. Must run AFTER splat_tiled (atomics vs plain stores).
// -------------------------------------------------------------------------
__global__ __launch_bounds__(256) void rescan_all(
        const float* __restrict__ img,
        const float* __restrict__ flo,
        float* __restrict__ out) {
    float* imgw  = out;
    float* o_out = out + NCHW;
    unsigned int j = blockIdx.x * blockDim.x + threadIdx.x;
    if (j >= (unsigned)(Nn * HW / 4)) return;
    int n   = j / (HW / 4);
    int q   = j - n * (HW / 4);
    int hw0 = q * 4;
    const fvec4 y4 = *(const fvec4*)&flo[(size_t)(n * 2 + 0) * HW + hw0];
    const fvec4 x4 = *(const fvec4*)&flo[(size_t)(n * 2 + 1) * HW + hw0];
    #pragma unroll
    for (int k = 0; k < 4; ++k) {
        float x = x4[k], y = y4[k];
        // skip iff the tiled pass owned the whole patch: flow in [-4,4) both axes
        if (x >= -(float)R && x < (float)R && y >= -(float)R && y < (float)R) continue;
        int hw = hw0 + k;
        int h = hw >> 10;            // Ww = 1024
        int w = hw & (Ww - 1);
        float x1f = floorf(x), y1f = floorf(y);
        float fx = x - x1f, fy = y - y1f;
        int bx = (int)x1f, by = (int)y1f;
        float i0 = img[(size_t)(n * Cc + 0) * HW + hw];
        float i1 = img[(size_t)(n * Cc + 1) * HW + hw];
        float i2 = img[(size_t)(n * Cc + 2) * HW + hw];
        const size_t nb = (size_t)n * Cc * HW;
        #pragma unroll
        for (int a = 0; a < 2; ++a) {
            #pragma unroll
            for (int b = 0; b < 2; ++b) {
                int ix = h + bx + a;
                int iy = w + by + b;
                if (ix < 0 || ix >= Hh || iy < 0 || iy >= Ww) continue;
                float dx = fx - (float)a, dy = fy - (float)b;
                float wt = __expf(-(dx * dx + dy * dy));
                int t = ix * Ww + iy;
                atomicAdd(&imgw[nb + t], i0 * wt);
                atomicAdd(&imgw[nb + HW + t], i1 * wt);
                atomicAdd(&imgw[nb + 2 * HW + t], i2 * wt);
                atomicAdd(&o_out[nb + t], wt);
                atomicAdd(&o_out[nb + HW + t], wt);
                atomicAdd(&o_out[nb + 2 * HW + t], wt);
            }
        }
    }
}

extern "C" void kernel_launch(void* const* d_in, const int* in_sizes, int n_in,
                              void* d_out, int out_size, void* d_ws, size_t ws_size,
                              hipStream_t stream) {
    const float* img = (const float*)d_in[0];
    const float* flo = (const float*)d_in[1];
    float* out = (float*)d_out;
    (void)d_ws; (void)ws_size;

    dim3 block(256);
    dim3 grid(32, 32, 8);   // remapped internally: n = linear%8 (XCD-local images)
    splat_tiled<<<grid, block, 0, stream>>>(img, flo, out);
    rescan_all<<<(Nn * HW / 4 + 255) / 256, 256, 0, stream>>>(img, flo, out);
}